// Round 2
// baseline (629.370 us; speedup 1.0000x reference)
//
#include <hip/hip_runtime.h>
#include <hip/hip_bf16.h>
#include <cstdint>
#include <cstddef>

// ---------------- types ----------------
typedef __bf16 bf16;
typedef __bf16 bf16x8 __attribute__((ext_vector_type(8)));
typedef __bf16 bf16x4 __attribute__((ext_vector_type(4)));
typedef float  f32x4  __attribute__((ext_vector_type(4)));

// Problem constants
#define TT 24
#define BB 128
#define EE 512
#define HH 512
#define VV 12000
#define VPAD 12032
#define THREEH 1536
#define MTOT (TT*BB)   // 3072
#define NBLK 32        // blocks in persistent GRU kernel (1/CU, all resident)

// global -> LDS direct copy, 16B per lane. LDS dest must be linear in lane order
// (per-wave base + lane*16B).
#define GLDS(gp, lp)                                                              \
  __builtin_amdgcn_global_load_lds(                                               \
      (const __attribute__((address_space(1))) void*)(const void*)(gp),           \
      (__attribute__((address_space(3))) void*)(void*)(lp), 16, 0, 0)

// ---------------- fused prep kernel ----------------
// region 0: X[m][e] (bf16)  m=t*128+b : t==0 -> img[b], else emb[cap[b][t-1]]
// region 1: W_ih -> bf16 ; region 2: W_hh -> bf16 ; region 3: W_out -> bf16 (+pad rows)
#define QX   (MTOT*EE/4)          // 393216
#define QIH  (THREEH*EE/4)        // 196608
#define QHH  (THREEH*HH/4)        // 196608
#define QOUT (VPAD*HH/4)          // 1540096
#define QTOT (QX+QIH+QHH+QOUT)    // 2326528

__global__ __launch_bounds__(256) void prep(const float* __restrict__ img,
                                            const int* __restrict__ cap,
                                            const float* __restrict__ emb,
                                            const float* __restrict__ W_ih,
                                            const float* __restrict__ W_hh,
                                            const float* __restrict__ W_out,
                                            bf16* __restrict__ X,
                                            bf16* __restrict__ Wih_b,
                                            bf16* __restrict__ Whh_b,
                                            bf16* __restrict__ Wout_b) {
  int q = blockIdx.x * 256 + threadIdx.x;
  if (q < QX) {
    int m = q >> 7, e4 = q & 127;
    int t = m >> 7, b = m & 127;
    const float* src;
    if (t == 0) src = img + (size_t)b * EE;
    else        src = emb + (size_t)cap[b * TT + (t - 1)] * EE;
    float4 v = *(const float4*)(src + e4 * 4);
    bf16x4 o = { (bf16)v.x, (bf16)v.y, (bf16)v.z, (bf16)v.w };
    *(bf16x4*)(X + (size_t)m * EE + e4 * 4) = o;
    return;
  }
  q -= QX;
  if (q < QIH) {
    float4 v = *(const float4*)(W_ih + (size_t)q * 4);
    bf16x4 o = { (bf16)v.x, (bf16)v.y, (bf16)v.z, (bf16)v.w };
    *(bf16x4*)(Wih_b + (size_t)q * 4) = o;
    return;
  }
  q -= QIH;
  if (q < QHH) {
    float4 v = *(const float4*)(W_hh + (size_t)q * 4);
    bf16x4 o = { (bf16)v.x, (bf16)v.y, (bf16)v.z, (bf16)v.w };
    *(bf16x4*)(Whh_b + (size_t)q * 4) = o;
    return;
  }
  q -= QHH;
  if (q < QOUT) {
    size_t i = (size_t)q * 4;
    float4 v = make_float4(0.f, 0.f, 0.f, 0.f);
    if (i + 4 <= (size_t)VV * HH) v = *(const float4*)(W_out + i);   // VV*HH % 4 == 0
    bf16x4 o = { (bf16)v.x, (bf16)v.y, (bf16)v.z, (bf16)v.w };
    *(bf16x4*)(Wout_b + i) = o;
  }
}

// ---------------- bf16 MFMA GEMM: C[m][n] = sum_k A[m][k]*B[n][k] (+bias) ----------------
// A: [M][512] bf16 row-major, B: [Npad][512] bf16 row-major ("B^T" GEMM).
// 128x128 tile, BK=32, 256 threads = 4 waves (2x2), each wave 4x4 16x16x32 frags.
// PERM=1: C row m = t*128+b is written to out[b*T*V + t*V + n], guarded n < Nvalid.
template <int PERM>
__global__ __launch_bounds__(256) void gemm_bt(const bf16* __restrict__ A,
                                               const bf16* __restrict__ Bm,
                                               const float* __restrict__ bias,
                                               float* __restrict__ C,
                                               int N, int Nvalid) {
  const int K = 512;
  __shared__ __align__(16) bf16 Alds[128 * 32];
  __shared__ __align__(16) bf16 Blds[128 * 32];
  const int tid  = threadIdx.x;
  const int lane = tid & 63;
  const int wv   = tid >> 6;
  const int wr   = wv >> 1, wc = wv & 1;
  const int m0 = blockIdx.y * 128, n0 = blockIdx.x * 128;
  const bf16* Ab = A + (size_t)m0 * K;
  const bf16* Bb = Bm + (size_t)n0 * K;
  const int srow = tid >> 2;             // 0..63
  const int skq  = (tid & 3) * 8;        // k offset in elems

  f32x4 acc[4][4];
#pragma unroll
  for (int i = 0; i < 4; i++)
#pragma unroll
    for (int j = 0; j < 4; j++) acc[i][j] = 0.f;

  for (int kt = 0; kt < K; kt += 32) {
    __syncthreads();
    GLDS(Ab + (size_t)srow * K + kt + skq,        Alds + srow * 32 + skq);
    GLDS(Ab + (size_t)(srow + 64) * K + kt + skq, Alds + (srow + 64) * 32 + skq);
    GLDS(Bb + (size_t)srow * K + kt + skq,        Blds + srow * 32 + skq);
    GLDS(Bb + (size_t)(srow + 64) * K + kt + skq, Blds + (srow + 64) * 32 + skq);
    asm volatile("s_waitcnt vmcnt(0)" ::: "memory");
    __syncthreads();

    const int fr = lane & 15, kh = lane >> 4;
    bf16x8 af[4], bfv[4];
#pragma unroll
    for (int i = 0; i < 4; i++)
      af[i] = *(const bf16x8*)(Alds + (wr * 64 + i * 16 + fr) * 32 + kh * 8);
#pragma unroll
    for (int j = 0; j < 4; j++)
      bfv[j] = *(const bf16x8*)(Blds + (wc * 64 + j * 16 + fr) * 32 + kh * 8);
#pragma unroll
    for (int i = 0; i < 4; i++)
#pragma unroll
      for (int j = 0; j < 4; j++)
        acc[i][j] = __builtin_amdgcn_mfma_f32_16x16x32_bf16(af[i], bfv[j], acc[i][j], 0, 0, 0);
  }

  const int fr = lane & 15, fq = lane >> 4;
#pragma unroll
  for (int j = 0; j < 4; j++) {
    int n = n0 + wc * 64 + j * 16 + fr;
    if (n >= Nvalid) continue;
    float bv = bias ? bias[n] : 0.f;
#pragma unroll
    for (int i = 0; i < 4; i++) {
#pragma unroll
      for (int r = 0; r < 4; r++) {
        int m = m0 + wr * 64 + i * 16 + fq * 4 + r;
        float v = acc[i][j][r] + bv;
        size_t off;
        if (PERM) off = (size_t)(m & 127) * (TT * (size_t)VV) + (size_t)(m >> 7) * VV + n;
        else      off = (size_t)m * N + n;
        C[off] = v;
      }
    }
  }
}

// ---------------- persistent GRU kernel: all 24 steps in one launch ----------------
// 32 blocks x 256 thr. Block owns 16 H-cols (j0) for all 3 gates, all 128 batch rows.
// W_hh slice (48 rows x 512) staged in LDS ONCE. fp32 h-state lives in registers
// (block owns same cols every step). Per-wave A staging (wave reads only its own
// 32 batch rows) -> no intra-step __syncthreads; dbuf with counted vmcnt.
// Steps separated by device-scope atomic grid barrier (all 32 blocks resident).
__global__ __launch_bounds__(256) void gru_all(bf16* __restrict__ hbA,
                                               bf16* __restrict__ hbB,
                                               const bf16* __restrict__ Whh_b,
                                               const float* __restrict__ gx,
                                               const float* __restrict__ b_hh,
                                               bf16* __restrict__ hs,
                                               unsigned* __restrict__ barcnt) {
  __shared__ __align__(16) bf16 Wlds[48 * 512];          // 48 KB
  __shared__ __align__(16) bf16 Alds[4][2][32 * 128];    // 64 KB (4 waves x dbuf)

  const int tid  = threadIdx.x;
  const int lane = tid & 63;
  const int wv   = tid >> 6;
  const int j0   = blockIdx.x * 16;

  // ---- stage W_hh slice: rows r=0..47 are W_hh rows (r/16)*512 + j0 + (r%16) ----
#pragma unroll
  for (int i = 0; i < 12; ++i) {
    int r   = i * 4 + (tid >> 6);
    int col = (tid & 63) * 8;
    int g = r >> 4, jj = r & 15;
    GLDS(Whh_b + ((size_t)(g * HH + j0 + jj)) * 512 + col, Wlds + r * 512 + col);
  }
  asm volatile("s_waitcnt vmcnt(0)" ::: "memory");
  __syncthreads();

  const int fr = lane & 15, kh = lane >> 4, fq = lane >> 4;
  const int j = j0 + fr;
  const float bh0 = b_hh[j], bh1 = b_hh[HH + j], bh2 = b_hh[2 * HH + j];

  float hreg[2][4];
#pragma unroll
  for (int mi = 0; mi < 2; mi++)
#pragma unroll
    for (int r = 0; r < 4; r++) hreg[mi][r] = 0.f;

  // per-wave A staging: wave wv's rows [wv*32, wv*32+32), cols [kc*128, +128)
  auto stageA = [&](const bf16* hin, int kc, int buf) {
#pragma unroll
    for (int i = 0; i < 8; ++i) {
      int rr = i * 4 + (lane >> 4);     // row within 32
      int cc = (lane & 15) * 8;         // col within 128
      GLDS(hin + (size_t)(wv * 32 + rr) * HH + kc * 128 + cc,
           &Alds[wv][buf][rr * 128 + cc]);
    }
  };

  for (int t = 0; t < TT; ++t) {
    f32x4 acc[2][3];
#pragma unroll
    for (int mi = 0; mi < 2; mi++)
#pragma unroll
      for (int g = 0; g < 3; g++) acc[mi][g] = 0.f;

    if (t > 0) {
      const bf16* hi = (t & 1) ? hbA : hbB;   // step t-1 wrote (t&1)? hbA : hbB
      stageA(hi, 0, 0);
#pragma unroll
      for (int kc = 0; kc < 4; ++kc) {
        const int buf = kc & 1;
        if (kc < 3) {
          stageA(hi, kc + 1, buf ^ 1);
          asm volatile("s_waitcnt vmcnt(8)" ::: "memory");
        } else {
          asm volatile("s_waitcnt vmcnt(0)" ::: "memory");
        }
#pragma unroll
        for (int kk = 0; kk < 4; ++kk) {
          bf16x8 af[2], bfv[3];
#pragma unroll
          for (int mi = 0; mi < 2; mi++)
            af[mi] = *(const bf16x8*)(&Alds[wv][buf][(mi * 16 + fr) * 128 + kk * 32 + kh * 8]);
#pragma unroll
          for (int g = 0; g < 3; g++)
            bfv[g] = *(const bf16x8*)(Wlds + (g * 16 + fr) * 512 + kc * 128 + kk * 32 + kh * 8);
#pragma unroll
          for (int mi = 0; mi < 2; mi++)
#pragma unroll
            for (int g = 0; g < 3; g++)
              acc[mi][g] = __builtin_amdgcn_mfma_f32_16x16x32_bf16(af[mi], bfv[g], acc[mi][g], 0, 0, 0);
        }
      }
    }

    // ---- gates + state update (acc: col=lane&15 -> j, row=fq*4+r -> batch) ----
    bf16* ho = (t & 1) ? hbB : hbA;
#pragma unroll
    for (int mi = 0; mi < 2; mi++) {
#pragma unroll
      for (int r = 0; r < 4; r++) {
        int bb  = wv * 32 + mi * 16 + fq * 4 + r;
        int row = t * BB + bb;
        float hr = acc[mi][0][r] + bh0;
        float hz = acc[mi][1][r] + bh1;
        float hn = acc[mi][2][r] + bh2;
        float xr = gx[(size_t)row * THREEH + j];
        float xz = gx[(size_t)row * THREEH + HH + j];
        float xn = gx[(size_t)row * THREEH + 2 * HH + j];
        float rg = 1.f / (1.f + __expf(-(xr + hr)));
        float zg = 1.f / (1.f + __expf(-(xz + hz)));
        float ng = tanhf(xn + rg * hn);
        float hnew = (1.f - zg) * ng + zg * hreg[mi][r];
        hreg[mi][r] = hnew;
        ho[(size_t)bb * HH + j] = (bf16)hnew;
        hs[(size_t)row * HH + j] = (bf16)hnew;
      }
    }

    // ---- grid barrier (release h writes, wait all blocks) ----
    if (t < TT - 1) {
      __threadfence();
      __syncthreads();
      if (tid == 0) {
        atomicAdd(barcnt, 1u);
        unsigned tgt = (unsigned)NBLK * (unsigned)(t + 1);
        while (__hip_atomic_load(barcnt, __ATOMIC_RELAXED, __HIP_MEMORY_SCOPE_AGENT) < tgt)
          __builtin_amdgcn_s_sleep(2);
        __threadfence();
      }
      __syncthreads();
    }
  }
}

// ---------------- launcher ----------------
extern "C" void kernel_launch(void* const* d_in, const int* in_sizes, int n_in,
                              void* d_out, int out_size, void* d_ws, size_t ws_size,
                              hipStream_t stream) {
  const float* img   = (const float*)d_in[0];
  const int*   cap   = (const int*)d_in[1];
  // d_in[2] = caplen (unused; static T)
  const float* emb   = (const float*)d_in[3];
  const float* W_ih  = (const float*)d_in[4];
  const float* W_hh  = (const float*)d_in[5];
  const float* b_ih  = (const float*)d_in[6];
  const float* b_hh  = (const float*)d_in[7];
  const float* W_out = (const float*)d_in[8];
  const float* b_out = (const float*)d_in[9];
  float* out = (float*)d_out;

  char* ws = (char*)d_ws;
  size_t off = 0;
  auto alloc = [&](size_t bytes) {
    void* p = ws + off;
    off = (off + bytes + 255) & ~(size_t)255;
    return p;
  };
  bf16*  X      = (bf16*)alloc((size_t)MTOT * EE * 2);        // 3.1 MB
  bf16*  Wih_b  = (bf16*)alloc((size_t)THREEH * EE * 2);      // 1.5 MB
  bf16*  Whh_b  = (bf16*)alloc((size_t)THREEH * HH * 2);      // 1.5 MB
  bf16*  Wout_b = (bf16*)alloc((size_t)VPAD * HH * 2);        // 12.3 MB
  float* gx     = (float*)alloc((size_t)MTOT * THREEH * 4);   // 18.9 MB
  bf16*  hs     = (bf16*)alloc((size_t)MTOT * HH * 2);        // 3.1 MB
  bf16*  hbA    = (bf16*)alloc((size_t)BB * HH * 2);          // 128 KB
  bf16*  hbB    = (bf16*)alloc((size_t)BB * HH * 2);          // 128 KB
  unsigned* barcnt = (unsigned*)alloc(256);

  hipMemsetAsync(barcnt, 0, 256, stream);

  prep<<<dim3((QTOT + 255) / 256), dim3(256), 0, stream>>>(
      img, cap, emb, W_ih, W_hh, W_out, X, Wih_b, Whh_b, Wout_b);

  // gx = X @ W_ih^T + b_ih   [3072][1536] fp32
  gemm_bt<0><<<dim3(THREEH / 128, MTOT / 128), dim3(256), 0, stream>>>(
      X, Wih_b, b_ih, gx, THREEH, THREEH);

  // all 24 GRU steps, one persistent kernel
  gru_all<<<dim3(NBLK), dim3(256), 0, stream>>>(hbA, hbB, Whh_b, gx, b_hh, hs, barcnt);

  // logits = hs @ W_out^T + b_out, permuted store to [B,T,V]
  gemm_bt<1><<<dim3(VPAD / 128, MTOT / 128), dim3(256), 0, stream>>>(
      hs, Wout_b, b_out, out, VV, VV);
}

// Round 4
// 431.187 us; speedup vs baseline: 1.4596x; 1.4596x over previous
//
#include <hip/hip_runtime.h>
#include <hip/hip_bf16.h>
#include <cstdint>
#include <cstddef>

// ---------------- types ----------------
typedef __bf16 bf16;
typedef __bf16 bf16x8 __attribute__((ext_vector_type(8)));
typedef __bf16 bf16x4 __attribute__((ext_vector_type(4)));
typedef float  f32x4  __attribute__((ext_vector_type(4)));

// Problem constants
#define TT 24
#define BB 128
#define EE 512
#define HH 512
#define VV 12000
#define VPAD 12032
#define THREEH 1536
#define MTOT (TT*BB)   // 3072
#define NBLK 32        // blocks in persistent GRU kernel (1/CU via LDS, all resident)

// global -> LDS direct copy, 16B per lane, LDS dest linear in lane order.
// aux=0:  normal caching (L1/L2)
// aux=17: SC0|SC1 -> bypass L1 and L2, read at MALL (coherent point). Used for
//         cross-XCD-shared h without any cache fences.
#define GLDS(gp, lp)                                                              \
  __builtin_amdgcn_global_load_lds(                                               \
      (const __attribute__((address_space(1))) void*)(const void*)(gp),           \
      (__attribute__((address_space(3))) void*)(void*)(lp), 16, 0, 0)
#define GLDS_COH(gp, lp)                                                          \
  __builtin_amdgcn_global_load_lds(                                               \
      (const __attribute__((address_space(1))) void*)(const void*)(gp),           \
      (__attribute__((address_space(3))) void*)(void*)(lp), 16, 0, 17)

// ---------------- fused prep kernel ----------------
#define QX   (MTOT*EE/4)          // 393216
#define QIH  (THREEH*EE/4)        // 196608
#define QHH  (THREEH*HH/4)        // 196608
#define QOUT (VPAD*HH/4)          // 1540096
#define QTOT (QX+QIH+QHH+QOUT)    // 2326528

__global__ __launch_bounds__(256) void prep(const float* __restrict__ img,
                                            const int* __restrict__ cap,
                                            const float* __restrict__ emb,
                                            const float* __restrict__ W_ih,
                                            const float* __restrict__ W_hh,
                                            const float* __restrict__ W_out,
                                            bf16* __restrict__ X,
                                            bf16* __restrict__ Wih_b,
                                            bf16* __restrict__ Whh_b,
                                            bf16* __restrict__ Wout_b) {
  int q = blockIdx.x * 256 + threadIdx.x;
  if (q < QX) {
    int m = q >> 7, e4 = q & 127;
    int t = m >> 7, b = m & 127;
    const float* src;
    if (t == 0) src = img + (size_t)b * EE;
    else        src = emb + (size_t)cap[b * TT + (t - 1)] * EE;
    float4 v = *(const float4*)(src + e4 * 4);
    bf16x4 o = { (bf16)v.x, (bf16)v.y, (bf16)v.z, (bf16)v.w };
    *(bf16x4*)(X + (size_t)m * EE + e4 * 4) = o;
    return;
  }
  q -= QX;
  if (q < QIH) {
    float4 v = *(const float4*)(W_ih + (size_t)q * 4);
    bf16x4 o = { (bf16)v.x, (bf16)v.y, (bf16)v.z, (bf16)v.w };
    *(bf16x4*)(Wih_b + (size_t)q * 4) = o;
    return;
  }
  q -= QIH;
  if (q < QHH) {
    float4 v = *(const float4*)(W_hh + (size_t)q * 4);
    bf16x4 o = { (bf16)v.x, (bf16)v.y, (bf16)v.z, (bf16)v.w };
    *(bf16x4*)(Whh_b + (size_t)q * 4) = o;
    return;
  }
  q -= QHH;
  if (q < QOUT) {
    size_t i = (size_t)q * 4;
    float4 v = make_float4(0.f, 0.f, 0.f, 0.f);
    if (i + 4 <= (size_t)VV * HH) v = *(const float4*)(W_out + i);   // VV*HH % 4 == 0
    bf16x4 o = { (bf16)v.x, (bf16)v.y, (bf16)v.z, (bf16)v.w };
    *(bf16x4*)(Wout_b + i) = o;
  }
}

// ---------------- bf16 MFMA GEMM: C[m][n] = sum_k A[m][k]*B[n][k] (+bias) ----------------
template <int PERM>
__global__ __launch_bounds__(256) void gemm_bt(const bf16* __restrict__ A,
                                               const bf16* __restrict__ Bm,
                                               const float* __restrict__ bias,
                                               float* __restrict__ C,
                                               int N, int Nvalid) {
  const int K = 512;
  __shared__ __align__(16) bf16 Alds[128 * 32];
  __shared__ __align__(16) bf16 Blds[128 * 32];
  const int tid  = threadIdx.x;
  const int lane = tid & 63;
  const int wv   = tid >> 6;
  const int wr   = wv >> 1, wc = wv & 1;
  const int m0 = blockIdx.y * 128, n0 = blockIdx.x * 128;
  const bf16* Ab = A + (size_t)m0 * K;
  const bf16* Bb = Bm + (size_t)n0 * K;
  const int srow = tid >> 2;             // 0..63
  const int skq  = (tid & 3) * 8;        // k offset in elems

  f32x4 acc[4][4];
#pragma unroll
  for (int i = 0; i < 4; i++)
#pragma unroll
    for (int j = 0; j < 4; j++) acc[i][j] = 0.f;

  for (int kt = 0; kt < K; kt += 32) {
    __syncthreads();
    GLDS(Ab + (size_t)srow * K + kt + skq,        Alds + srow * 32 + skq);
    GLDS(Ab + (size_t)(srow + 64) * K + kt + skq, Alds + (srow + 64) * 32 + skq);
    GLDS(Bb + (size_t)srow * K + kt + skq,        Blds + srow * 32 + skq);
    GLDS(Bb + (size_t)(srow + 64) * K + kt + skq, Blds + (srow + 64) * 32 + skq);
    asm volatile("s_waitcnt vmcnt(0)" ::: "memory");
    __syncthreads();

    const int fr = lane & 15, kh = lane >> 4;
    bf16x8 af[4], bfv[4];
#pragma unroll
    for (int i = 0; i < 4; i++)
      af[i] = *(const bf16x8*)(Alds + (wr * 64 + i * 16 + fr) * 32 + kh * 8);
#pragma unroll
    for (int j = 0; j < 4; j++)
      bfv[j] = *(const bf16x8*)(Blds + (wc * 64 + j * 16 + fr) * 32 + kh * 8);
#pragma unroll
    for (int i = 0; i < 4; i++)
#pragma unroll
      for (int j = 0; j < 4; j++)
        acc[i][j] = __builtin_amdgcn_mfma_f32_16x16x32_bf16(af[i], bfv[j], acc[i][j], 0, 0, 0);
  }

  const int fr = lane & 15, fq = lane >> 4;
#pragma unroll
  for (int j = 0; j < 4; j++) {
    int n = n0 + wc * 64 + j * 16 + fr;
    if (n >= Nvalid) continue;
    float bv = bias ? bias[n] : 0.f;
#pragma unroll
    for (int i = 0; i < 4; i++) {
#pragma unroll
      for (int r = 0; r < 4; r++) {
        int m = m0 + wr * 64 + i * 16 + fq * 4 + r;
        float v = acc[i][j][r] + bv;
        size_t off;
        if (PERM) off = (size_t)(m & 127) * (TT * (size_t)VV) + (size_t)(m >> 7) * VV + n;
        else      off = (size_t)m * N + n;
        C[off] = v;
      }
    }
  }
}

// ---------------- persistent GRU kernel: all 24 steps in one launch ----------------
// 32 blocks x 256 thr. Block owns 16 H-cols for all 3 gates, all 128 batch rows.
// W_hh slice staged in LDS once (XOR-swizzled via ds_write). h exchanged through
// MALL: sc0|sc1 atomic u32 stores (LINEAR layout) + sc0|sc1 global_load_lds with
// per-lane XOR'd SOURCE address (swizzle-on-read) -> LDS holds swizzled h, frag
// reads XOR to match. NO cache fences anywhere.
// Barrier: syncthreads (drains stores) -> relaxed agent atomicAdd -> relaxed spin.
__global__ __launch_bounds__(256) void gru_all(unsigned* __restrict__ HswA,
                                               unsigned* __restrict__ HswB,
                                               const bf16* __restrict__ Whh_b,
                                               const float* __restrict__ gx,
                                               const float* __restrict__ b_hh,
                                               bf16* __restrict__ hs,
                                               unsigned* __restrict__ barcnt) {
  __shared__ __align__(16) bf16 Wlds[48 * 512];          // 48 KB, swizzled
  __shared__ __align__(16) bf16 Alds[4][2][32 * 128];    // 64 KB (4 waves x dbuf), swizzled

  const int tid  = threadIdx.x;
  const int lane = tid & 63;
  const int wv   = tid >> 6;
  const int j0   = blockIdx.x * 16;
  const int fr   = lane & 15;
  const int kh   = lane >> 4;          // 0..3 (k-half for frags / row group for staging)
  const int j    = j0 + fr;

  // ---- stage W_hh slice into swizzled LDS via registers (once) ----
  // row r=0..47 of Wlds = W_hh row (r/16)*512 + j0 + (r%16); byte col c stored at
  // r*1024 + (c ^ ((r&7)<<4)).
#pragma unroll
  for (int i = 0; i < 12; ++i) {
    int r  = i * 4 + wv;
    int g  = r >> 4, jj = r & 15;
    bf16x8 v = *(const bf16x8*)(Whh_b + (size_t)(g * HH + j0 + jj) * 512 + lane * 8);
    int dst = r * 1024 + ((lane * 16) ^ ((r & 7) << 4));
    *(bf16x8*)((char*)Wlds + dst) = v;
  }
  __syncthreads();

  const float bh0 = b_hh[j], bh1 = b_hh[HH + j], bh2 = b_hh[2 * HH + j];

  float hreg[2][4];
#pragma unroll
  for (int mi = 0; mi < 2; mi++)
#pragma unroll
    for (int r = 0; r < 4; r++) hreg[mi][r] = 0.f;

  // per-wave A staging from LINEAR global h with swizzle-on-read:
  // lane L: rr=i*4+(L>>4), cc=(L&15)*8 -> global elem
  //   (wv*32+rr)*512 + kc*128 + (cc ^ ((rr&7)<<3)),
  // LDS dest linear (base + L*16B) -> LDS[rr][cc] = h[bb][cc ^ sw]  (swizzled).
  auto stageA = [&](const unsigned* hin, int kc, int buf) {
    const bf16* hb = (const bf16*)hin;
#pragma unroll
    for (int i = 0; i < 8; ++i) {
      int rr = i * 4 + kh;
      int cc = fr * 8;
      int src = (wv * 32 + rr) * 512 + kc * 128 + (cc ^ ((rr & 7) << 3));
      GLDS_COH(hb + src, &Alds[wv][buf][0] + rr * 128 + cc);
    }
  };

  for (int t = 0; t < TT; ++t) {
    // ---- prefetch gx for this step (hides under staging/MFMA) ----
    float pxr[2][4], pxz[2][4], pxn[2][4];
#pragma unroll
    for (int mi = 0; mi < 2; mi++)
#pragma unroll
      for (int r = 0; r < 4; r++) {
        int bb = wv * 32 + mi * 16 + kh * 4 + r;
        const float* gb = gx + (size_t)(t * BB + bb) * THREEH + j;
        pxr[mi][r] = gb[0];
        pxz[mi][r] = gb[512];
        pxn[mi][r] = gb[1024];
      }

    f32x4 acc[2][3];
#pragma unroll
    for (int mi = 0; mi < 2; mi++)
#pragma unroll
      for (int g = 0; g < 3; g++) acc[mi][g] = 0.f;

    if (t > 0) {
      const unsigned* hi = (t & 1) ? HswA : HswB;   // step t-1 wrote (t odd ? A : B)
      stageA(hi, 0, 0);
#pragma unroll
      for (int kc = 0; kc < 4; ++kc) {
        const int buf = kc & 1;
        if (kc < 3) {
          stageA(hi, kc + 1, buf ^ 1);
          asm volatile("s_waitcnt vmcnt(8)" ::: "memory");
        } else {
          asm volatile("s_waitcnt vmcnt(0)" ::: "memory");
        }
#pragma unroll
        for (int kk = 0; kk < 4; ++kk) {
          bf16x8 af[2], bfv[3];
#pragma unroll
          for (int mi = 0; mi < 2; mi++)
            af[mi] = *(const bf16x8*)((char*)&Alds[wv][buf][0] +
                       (mi * 16 + fr) * 256 + ((kk * 64 + kh * 16) ^ ((fr & 7) << 4)));
#pragma unroll
          for (int g = 0; g < 3; g++)
            bfv[g] = *(const bf16x8*)((char*)Wlds + (g * 16 + fr) * 1024 +
                       ((kc * 256 + kk * 64 + kh * 16) ^ ((fr & 7) << 4)));
#pragma unroll
          for (int mi = 0; mi < 2; mi++)
#pragma unroll
            for (int g = 0; g < 3; g++)
              acc[mi][g] = __builtin_amdgcn_mfma_f32_16x16x32_bf16(af[mi], bfv[g], acc[mi][g], 0, 0, 0);
        }
      }
    }

    // ---- gates + state update ----
    unsigned* ho = (t & 1) ? HswB : HswA;
    unsigned* hs32 = (unsigned*)hs;
#pragma unroll
    for (int mi = 0; mi < 2; mi++) {
#pragma unroll
      for (int r = 0; r < 4; r++) {
        int bb  = wv * 32 + mi * 16 + kh * 4 + r;
        int row = t * BB + bb;
        float hr = acc[mi][0][r] + bh0;
        float hz = acc[mi][1][r] + bh1;
        float hn = acc[mi][2][r] + bh2;
        float rg = 1.f / (1.f + __expf(-(pxr[mi][r] + hr)));
        float zg = 1.f / (1.f + __expf(-(pxz[mi][r] + hz)));
        float ng = tanhf(pxn[mi][r] + rg * hn);
        float hnew = (1.f - zg) * ng + zg * hreg[mi][r];
        hreg[mi][r] = hnew;
        // pack (j even, j odd) into u32 via partner-lane shuffle
        unsigned mine  = (unsigned)__builtin_bit_cast(unsigned short, (bf16)hnew);
        unsigned other = (unsigned)__shfl_xor((int)mine, 1);
        if (!(lane & 1)) {
          unsigned word = mine | (other << 16);
          // LINEAR h layout, coherent at MALL (no fences needed)
          int elem = bb * 512 + j;
          __hip_atomic_store(&ho[elem >> 1], word, __ATOMIC_RELAXED, __HIP_MEMORY_SCOPE_AGENT);
          // plain hs for the output GEMM
          hs32[((size_t)row * 512 + j) >> 1] = word;
        }
      }
    }

    // ---- grid barrier: syncthreads drains stores, then relaxed agent add+spin ----
    if (t < TT - 1) {
      __syncthreads();
      if (tid == 0) {
        __hip_atomic_fetch_add(barcnt, 1u, __ATOMIC_RELAXED, __HIP_MEMORY_SCOPE_AGENT);
        unsigned tgt = (unsigned)NBLK * (unsigned)(t + 1);
        while (__hip_atomic_load(barcnt, __ATOMIC_RELAXED, __HIP_MEMORY_SCOPE_AGENT) < tgt)
          __builtin_amdgcn_s_sleep(2);
      }
      __syncthreads();
    }
  }
}

// ---------------- launcher ----------------
extern "C" void kernel_launch(void* const* d_in, const int* in_sizes, int n_in,
                              void* d_out, int out_size, void* d_ws, size_t ws_size,
                              hipStream_t stream) {
  const float* img   = (const float*)d_in[0];
  const int*   cap   = (const int*)d_in[1];
  // d_in[2] = caplen (unused; static T)
  const float* emb   = (const float*)d_in[3];
  const float* W_ih  = (const float*)d_in[4];
  const float* W_hh  = (const float*)d_in[5];
  const float* b_ih  = (const float*)d_in[6];
  const float* b_hh  = (const float*)d_in[7];
  const float* W_out = (const float*)d_in[8];
  const float* b_out = (const float*)d_in[9];
  float* out = (float*)d_out;

  char* ws = (char*)d_ws;
  size_t off = 0;
  auto alloc = [&](size_t bytes) {
    void* p = ws + off;
    off = (off + bytes + 255) & ~(size_t)255;
    return p;
  };
  bf16*  X      = (bf16*)alloc((size_t)MTOT * EE * 2);        // 3.1 MB
  bf16*  Wih_b  = (bf16*)alloc((size_t)THREEH * EE * 2);      // 1.5 MB
  bf16*  Whh_b  = (bf16*)alloc((size_t)THREEH * HH * 2);      // 1.5 MB
  bf16*  Wout_b = (bf16*)alloc((size_t)VPAD * HH * 2);        // 12.3 MB
  float* gx     = (float*)alloc((size_t)MTOT * THREEH * 4);   // 18.9 MB
  bf16*  hs     = (bf16*)alloc((size_t)MTOT * HH * 2);        // 3.1 MB
  unsigned* HswA = (unsigned*)alloc((size_t)BB * HH * 2);     // 128 KB
  unsigned* HswB = (unsigned*)alloc((size_t)BB * HH * 2);     // 128 KB
  unsigned* barcnt = (unsigned*)alloc(256);

  hipMemsetAsync(barcnt, 0, 256, stream);

  prep<<<dim3((QTOT + 255) / 256), dim3(256), 0, stream>>>(
      img, cap, emb, W_ih, W_hh, W_out, X, Wih_b, Whh_b, Wout_b);

  // gx = X @ W_ih^T + b_ih   [3072][1536] fp32
  gemm_bt<0><<<dim3(THREEH / 128, MTOT / 128), dim3(256), 0, stream>>>(
      X, Wih_b, b_ih, gx, THREEH, THREEH);

  // all 24 GRU steps, one persistent kernel
  gru_all<<<dim3(NBLK), dim3(256), 0, stream>>>(HswA, HswB, Whh_b, gx, b_hh, hs, barcnt);

  // logits = hs @ W_out^T + b_out, permuted store to [B,T,V]
  gemm_bt<1><<<dim3(VPAD / 128, MTOT / 128), dim3(256), 0, stream>>>(
      hs, Wout_b, b_out, out, VV, VV);
}

// Round 5
// 425.414 us; speedup vs baseline: 1.4794x; 1.0136x over previous
//
#include <hip/hip_runtime.h>
#include <hip/hip_bf16.h>
#include <cstdint>
#include <cstddef>

// ---------------- types ----------------
typedef __bf16 bf16;
typedef __bf16 bf16x8 __attribute__((ext_vector_type(8)));
typedef __bf16 bf16x4 __attribute__((ext_vector_type(4)));
typedef float  f32x4  __attribute__((ext_vector_type(4)));

// Problem constants
#define TT 24
#define BB 128
#define EE 512
#define HH 512
#define VV 12000
#define VPAD 12032
#define THREEH 1536
#define MTOT (TT*BB)   // 3072
#define NBLK 32        // blocks in persistent GRU kernel (1/CU via LDS, all resident)

// global -> LDS direct copy, 16B per lane, LDS dest linear in lane order.
// aux=17: SC0|SC1 -> bypass L1/L2, read at MALL (coherent point) -> fence-free
//         cross-XCD h exchange.
#define GLDS(gp, lp)                                                              \
  __builtin_amdgcn_global_load_lds(                                               \
      (const __attribute__((address_space(1))) void*)(const void*)(gp),           \
      (__attribute__((address_space(3))) void*)(void*)(lp), 16, 0, 0)
#define GLDS_COH(gp, lp)                                                          \
  __builtin_amdgcn_global_load_lds(                                               \
      (const __attribute__((address_space(1))) void*)(const void*)(gp),           \
      (__attribute__((address_space(3))) void*)(void*)(lp), 16, 0, 17)

// ---------------- fused prep kernel ----------------
#define QX   (MTOT*EE/4)          // 393216
#define QIH  (THREEH*EE/4)        // 196608
#define QHH  (THREEH*HH/4)        // 196608
#define QOUT (VPAD*HH/4)          // 1540096
#define QTOT (QX+QIH+QHH+QOUT)    // 2326528

__global__ __launch_bounds__(256) void prep(const float* __restrict__ img,
                                            const int* __restrict__ cap,
                                            const float* __restrict__ emb,
                                            const float* __restrict__ W_ih,
                                            const float* __restrict__ W_hh,
                                            const float* __restrict__ W_out,
                                            bf16* __restrict__ X,
                                            bf16* __restrict__ Wih_b,
                                            bf16* __restrict__ Whh_b,
                                            bf16* __restrict__ Wout_b) {
  int q = blockIdx.x * 256 + threadIdx.x;
  if (q < QX) {
    int m = q >> 7, e4 = q & 127;
    int t = m >> 7, b = m & 127;
    const float* src;
    if (t == 0) src = img + (size_t)b * EE;
    else        src = emb + (size_t)cap[b * TT + (t - 1)] * EE;
    float4 v = *(const float4*)(src + e4 * 4);
    bf16x4 o = { (bf16)v.x, (bf16)v.y, (bf16)v.z, (bf16)v.w };
    *(bf16x4*)(X + (size_t)m * EE + e4 * 4) = o;
    return;
  }
  q -= QX;
  if (q < QIH) {
    float4 v = *(const float4*)(W_ih + (size_t)q * 4);
    bf16x4 o = { (bf16)v.x, (bf16)v.y, (bf16)v.z, (bf16)v.w };
    *(bf16x4*)(Wih_b + (size_t)q * 4) = o;
    return;
  }
  q -= QIH;
  if (q < QHH) {
    float4 v = *(const float4*)(W_hh + (size_t)q * 4);
    bf16x4 o = { (bf16)v.x, (bf16)v.y, (bf16)v.z, (bf16)v.w };
    *(bf16x4*)(Whh_b + (size_t)q * 4) = o;
    return;
  }
  q -= QHH;
  if (q < QOUT) {
    size_t i = (size_t)q * 4;
    float4 v = make_float4(0.f, 0.f, 0.f, 0.f);
    if (i + 4 <= (size_t)VV * HH) v = *(const float4*)(W_out + i);   // VV*HH % 4 == 0
    bf16x4 o = { (bf16)v.x, (bf16)v.y, (bf16)v.z, (bf16)v.w };
    *(bf16x4*)(Wout_b + i) = o;
  }
}

// ---------------- bf16 MFMA GEMM: C[m][n] = sum_k A[m][k]*B[n][k] (+bias) ----------------
// 128x128 tile, BK=32, 4 waves. XCD-aware bijective swizzle (nwg % 8 == 0).
template <int PERM>
__global__ __launch_bounds__(256) void gemm_bt(const bf16* __restrict__ A,
                                               const bf16* __restrict__ Bm,
                                               const float* __restrict__ bias,
                                               float* __restrict__ C,
                                               int N, int Nvalid) {
  const int K = 512;
  __shared__ __align__(16) bf16 Alds[128 * 32];
  __shared__ __align__(16) bf16 Blds[128 * 32];
  const int tid  = threadIdx.x;
  const int lane = tid & 63;
  const int wv   = tid >> 6;
  const int wr   = wv >> 1, wc = wv & 1;

  // XCD swizzle: consecutive swizzled ids share an XCD -> L2 reuse of A/B panels.
  const int nwg = gridDim.x * gridDim.y;
  const int wid = blockIdx.y * gridDim.x + blockIdx.x;
  const int cpx = nwg >> 3;
  const int swz = (wid & 7) * cpx + (wid >> 3);
  const int bx = swz % gridDim.x, by = swz / gridDim.x;

  const int m0 = by * 128, n0 = bx * 128;
  const bf16* Ab = A + (size_t)m0 * K;
  const bf16* Bb = Bm + (size_t)n0 * K;
  const int srow = tid >> 2;             // 0..63
  const int skq  = (tid & 3) * 8;        // k offset in elems

  f32x4 acc[4][4];
#pragma unroll
  for (int i = 0; i < 4; i++)
#pragma unroll
    for (int j = 0; j < 4; j++) acc[i][j] = 0.f;

  for (int kt = 0; kt < K; kt += 32) {
    __syncthreads();
    GLDS(Ab + (size_t)srow * K + kt + skq,        Alds + srow * 32 + skq);
    GLDS(Ab + (size_t)(srow + 64) * K + kt + skq, Alds + (srow + 64) * 32 + skq);
    GLDS(Bb + (size_t)srow * K + kt + skq,        Blds + srow * 32 + skq);
    GLDS(Bb + (size_t)(srow + 64) * K + kt + skq, Blds + (srow + 64) * 32 + skq);
    asm volatile("s_waitcnt vmcnt(0)" ::: "memory");
    __syncthreads();

    const int fr = lane & 15, kh = lane >> 4;
    bf16x8 af[4], bfv[4];
#pragma unroll
    for (int i = 0; i < 4; i++)
      af[i] = *(const bf16x8*)(Alds + (wr * 64 + i * 16 + fr) * 32 + kh * 8);
#pragma unroll
    for (int j = 0; j < 4; j++)
      bfv[j] = *(const bf16x8*)(Blds + (wc * 64 + j * 16 + fr) * 32 + kh * 8);
#pragma unroll
    for (int i = 0; i < 4; i++)
#pragma unroll
      for (int j = 0; j < 4; j++)
        acc[i][j] = __builtin_amdgcn_mfma_f32_16x16x32_bf16(af[i], bfv[j], acc[i][j], 0, 0, 0);
  }

  const int fr = lane & 15, fq = lane >> 4;
#pragma unroll
  for (int j = 0; j < 4; j++) {
    int n = n0 + wc * 64 + j * 16 + fr;
    if (n >= Nvalid) continue;
    float bv = bias ? bias[n] : 0.f;
#pragma unroll
    for (int i = 0; i < 4; i++) {
#pragma unroll
      for (int r = 0; r < 4; r++) {
        int m = m0 + wr * 64 + i * 16 + fq * 4 + r;
        float v = acc[i][j][r] + bv;
        size_t off;
        if (PERM) off = (size_t)(m & 127) * (TT * (size_t)VV) + (size_t)(m >> 7) * VV + n;
        else      off = (size_t)m * N + n;
        C[off] = v;
      }
    }
  }
}

// ---------------- persistent GRU kernel: all 24 steps in one launch ----------------
// 32 blocks x 256 thr. Block owns 16 H-cols for all 3 gates, all 128 batch rows.
// W_hh slice in LDS once (XOR-swizzled). h exchange via MALL (sc0|sc1 stores +
// aux=17 global_load_lds with swizzle-on-read source). 3-buffer look-ahead
// staging (one exposed MALL latency). Distributed per-step flag barrier with
// lane-parallel poll; next-step gx prefetch overlaps the barrier wait.
__global__ __launch_bounds__(256) void gru_all(unsigned* __restrict__ HswA,
                                               unsigned* __restrict__ HswB,
                                               const bf16* __restrict__ Whh_b,
                                               const float* __restrict__ gx,
                                               const float* __restrict__ b_hh,
                                               bf16* __restrict__ hs,
                                               unsigned* __restrict__ flags) {
  __shared__ __align__(16) bf16 Wlds[48 * 512];          // 48 KB, swizzled
  __shared__ __align__(16) bf16 Alds[4][3][32 * 128];    // 96 KB (4 waves x 3 bufs)

  const int tid  = threadIdx.x;
  const int lane = tid & 63;
  const int wv   = tid >> 6;
  const int j0   = blockIdx.x * 16;
  const int fr   = lane & 15;
  const int kh   = lane >> 4;
  const int j    = j0 + fr;

  // ---- stage W_hh slice into swizzled LDS (once) ----
#pragma unroll
  for (int i = 0; i < 12; ++i) {
    int r  = i * 4 + wv;
    int g  = r >> 4, jj = r & 15;
    bf16x8 v = *(const bf16x8*)(Whh_b + (size_t)(g * HH + j0 + jj) * 512 + lane * 8);
    int dst = r * 1024 + ((lane * 16) ^ ((r & 7) << 4));
    *(bf16x8*)((char*)Wlds + dst) = v;
  }
  __syncthreads();

  const float bh0 = b_hh[j], bh1 = b_hh[HH + j], bh2 = b_hh[2 * HH + j];

  float hreg[2][4];
#pragma unroll
  for (int mi = 0; mi < 2; mi++)
#pragma unroll
    for (int r = 0; r < 4; r++) hreg[mi][r] = 0.f;

  // per-wave A staging from LINEAR global h with swizzle-on-read source addr.
  auto stageA = [&](const unsigned* hin, int kc, int buf) {
    const bf16* hb = (const bf16*)hin;
#pragma unroll
    for (int i = 0; i < 8; ++i) {
      int rr = i * 4 + kh;
      int cc = fr * 8;
      int src = (wv * 32 + rr) * 512 + kc * 128 + (cc ^ ((rr & 7) << 3));
      GLDS_COH(hb + src, &Alds[wv][buf][0] + rr * 128 + cc);
    }
  };

  f32x4 acc[2][3];
  auto computeKC = [&](int kc, int buf) {
#pragma unroll
    for (int kk = 0; kk < 4; ++kk) {
      bf16x8 af[2], bfv[3];
#pragma unroll
      for (int mi = 0; mi < 2; mi++)
        af[mi] = *(const bf16x8*)((char*)&Alds[wv][buf][0] +
                   (mi * 16 + fr) * 256 + ((kk * 64 + kh * 16) ^ ((fr & 7) << 4)));
#pragma unroll
      for (int g = 0; g < 3; g++)
        bfv[g] = *(const bf16x8*)((char*)Wlds + (g * 16 + fr) * 1024 +
                   ((kc * 256 + kk * 64 + kh * 16) ^ ((fr & 7) << 4)));
#pragma unroll
      for (int mi = 0; mi < 2; mi++)
#pragma unroll
        for (int g = 0; g < 3; g++)
          acc[mi][g] = __builtin_amdgcn_mfma_f32_16x16x32_bf16(af[mi], bfv[g], acc[mi][g], 0, 0, 0);
    }
  };

  // gx prefetch registers (loaded one step ahead; hides under barrier wait)
  float pxr[2][4], pxz[2][4], pxn[2][4];
  auto prefetchGX = [&](int t) {
#pragma unroll
    for (int mi = 0; mi < 2; mi++)
#pragma unroll
      for (int r = 0; r < 4; r++) {
        int bb = wv * 32 + mi * 16 + kh * 4 + r;
        const float* gb = gx + (size_t)(t * BB + bb) * THREEH + j;
        pxr[mi][r] = gb[0];
        pxz[mi][r] = gb[512];
        pxn[mi][r] = gb[1024];
      }
  };
  prefetchGX(0);

  for (int t = 0; t < TT; ++t) {
#pragma unroll
    for (int mi = 0; mi < 2; mi++)
#pragma unroll
      for (int g = 0; g < 3; g++) acc[mi][g] = 0.f;

    if (t > 0) {
      const unsigned* hi = (t & 1) ? HswA : HswB;   // step t-1 wrote (t odd ? A : B)
      // issue 3 chunks upfront (24 stage loads in flight)
      stageA(hi, 0, 0);
      stageA(hi, 1, 1);
      stageA(hi, 2, 2);
      asm volatile("s_waitcnt vmcnt(16)" ::: "memory");   // kc0 landed
      computeKC(0, 0);
      // reuse buf0 for kc3: ensure kc0's ds_reads retired before LDS overwrite
      asm volatile("s_waitcnt lgkmcnt(0)" ::: "memory");
      __builtin_amdgcn_sched_barrier(0);
      stageA(hi, 3, 0);
      asm volatile("s_waitcnt vmcnt(16)" ::: "memory");   // kc1 landed
      computeKC(1, 1);
      asm volatile("s_waitcnt vmcnt(8)" ::: "memory");    // kc2 landed
      computeKC(2, 2);
      asm volatile("s_waitcnt vmcnt(0)" ::: "memory");    // kc3 landed
      computeKC(3, 0);
    }

    // ---- gates + state update (uses gx prefetched last iteration) ----
    unsigned* ho = (t & 1) ? HswB : HswA;
    unsigned* hs32 = (unsigned*)hs;
#pragma unroll
    for (int mi = 0; mi < 2; mi++) {
#pragma unroll
      for (int r = 0; r < 4; r++) {
        int bb  = wv * 32 + mi * 16 + kh * 4 + r;
        int row = t * BB + bb;
        float hr = acc[mi][0][r] + bh0;
        float hz = acc[mi][1][r] + bh1;
        float hn = acc[mi][2][r] + bh2;
        float rg = 1.f / (1.f + __expf(-(pxr[mi][r] + hr)));
        float zg = 1.f / (1.f + __expf(-(pxz[mi][r] + hz)));
        float ng = tanhf(pxn[mi][r] + rg * hn);
        float hnew = (1.f - zg) * ng + zg * hreg[mi][r];
        hreg[mi][r] = hnew;
        unsigned mine  = (unsigned)__builtin_bit_cast(unsigned short, (bf16)hnew);
        unsigned other = (unsigned)__shfl_xor((int)mine, 1);
        if (!(lane & 1)) {
          unsigned word = mine | (other << 16);
          int elem = bb * 512 + j;
          __hip_atomic_store(&ho[elem >> 1], word, __ATOMIC_RELAXED, __HIP_MEMORY_SCOPE_AGENT);
          hs32[((size_t)row * 512 + j) >> 1] = word;
        }
      }
    }

    // ---- distributed flag barrier; gx(t+1) prefetch overlaps the wait ----
    if (t < TT - 1) {
      __syncthreads();   // drains vmcnt -> h stores at MALL before signal
      if (tid == 0)
        __hip_atomic_store(&flags[(t * NBLK + blockIdx.x) * 4], 1u,
                           __ATOMIC_RELAXED, __HIP_MEMORY_SCOPE_AGENT);
      prefetchGX(t + 1);
      if (wv == 0 && lane < NBLK) {
        while (__hip_atomic_load(&flags[(t * NBLK + lane) * 4],
                                 __ATOMIC_RELAXED, __HIP_MEMORY_SCOPE_AGENT) == 0)
          __builtin_amdgcn_s_sleep(1);
      }
      __syncthreads();
    }
  }
}

// ---------------- launcher ----------------
extern "C" void kernel_launch(void* const* d_in, const int* in_sizes, int n_in,
                              void* d_out, int out_size, void* d_ws, size_t ws_size,
                              hipStream_t stream) {
  const float* img   = (const float*)d_in[0];
  const int*   cap   = (const int*)d_in[1];
  // d_in[2] = caplen (unused; static T)
  const float* emb   = (const float*)d_in[3];
  const float* W_ih  = (const float*)d_in[4];
  const float* W_hh  = (const float*)d_in[5];
  const float* b_ih  = (const float*)d_in[6];
  const float* b_hh  = (const float*)d_in[7];
  const float* W_out = (const float*)d_in[8];
  const float* b_out = (const float*)d_in[9];
  float* out = (float*)d_out;

  char* ws = (char*)d_ws;
  size_t off = 0;
  auto alloc = [&](size_t bytes) {
    void* p = ws + off;
    off = (off + bytes + 255) & ~(size_t)255;
    return p;
  };
  bf16*  X      = (bf16*)alloc((size_t)MTOT * EE * 2);        // 3.1 MB
  bf16*  Wih_b  = (bf16*)alloc((size_t)THREEH * EE * 2);      // 1.5 MB
  bf16*  Whh_b  = (bf16*)alloc((size_t)THREEH * HH * 2);      // 1.5 MB
  bf16*  Wout_b = (bf16*)alloc((size_t)VPAD * HH * 2);        // 12.3 MB
  float* gx     = (float*)alloc((size_t)MTOT * THREEH * 4);   // 18.9 MB
  bf16*  hs     = (bf16*)alloc((size_t)MTOT * HH * 2);        // 3.1 MB
  unsigned* HswA = (unsigned*)alloc((size_t)BB * HH * 2);     // 128 KB
  unsigned* HswB = (unsigned*)alloc((size_t)BB * HH * 2);     // 128 KB
  unsigned* flags = (unsigned*)alloc((size_t)TT * NBLK * 16); // 12 KB

  hipMemsetAsync(flags, 0, (size_t)TT * NBLK * 16, stream);

  prep<<<dim3((QTOT + 255) / 256), dim3(256), 0, stream>>>(
      img, cap, emb, W_ih, W_hh, W_out, X, Wih_b, Whh_b, Wout_b);

  // gx = X @ W_ih^T + b_ih   [3072][1536] fp32
  gemm_bt<0><<<dim3(THREEH / 128, MTOT / 128), dim3(256), 0, stream>>>(
      X, Wih_b, b_ih, gx, THREEH, THREEH);

  // all 24 GRU steps, one persistent kernel
  gru_all<<<dim3(NBLK), dim3(256), 0, stream>>>(HswA, HswB, Whh_b, gx, b_hh, hs, flags);

  // logits = hs @ W_out^T + b_out, permuted store to [B,T,V]
  gemm_bt<1><<<dim3(VPAD / 128, MTOT / 128), dim3(256), 0, stream>>>(
      hs, Wout_b, b_out, out, VV, VV);
}